// Round 1
// baseline (192.185 us; speedup 1.0000x reference)
//
#include <hip/hip_runtime.h>
#include <stdint.h>

typedef __attribute__((ext_vector_type(8))) short short8;
typedef __attribute__((ext_vector_type(4))) float floatx4;

#define W_DIM 900
#define PADW  1024
#define DDIM  1024
#define NPAD  450

__device__ __forceinline__ unsigned short f2bf(float f) {
  unsigned int u = __builtin_bit_cast(unsigned int, f);
  u += 0x7fffu + ((u >> 16) & 1u);   // round-to-nearest-even
  return (unsigned short)(u >> 16);
}

__device__ __forceinline__ void async16(const void* g, void* l) {
  __builtin_amdgcn_global_load_lds(
      (const __attribute__((address_space(1))) void*)g,
      (__attribute__((address_space(3))) void*)l, 16, 0, 0);
}

// ---------------------------------------------------------------------------
// Convert + transpose + pad:
//   in[b,h,w,c] fp32  ->  dst[b, w, h*256 + c] bf16, w padded 900->1024 (zeros)
// grid (1024, 16, 2), block 256. Coalesced float4 reads, ushort4 writes.
// ---------------------------------------------------------------------------
__global__ void convert_kernel(const float* __restrict__ in1,
                               const float* __restrict__ in2,
                               unsigned short* __restrict__ dA,
                               unsigned short* __restrict__ dB) {
  const int w = blockIdx.x;
  const int b = blockIdx.y;
  const float* __restrict__ src = blockIdx.z ? in2 : in1;
  unsigned short* __restrict__ dst = blockIdx.z ? dB : dA;

  const int t  = threadIdx.x;          // 0..255
  const int h  = t >> 6;               // 0..3
  const int c4 = (t & 63) << 2;        // 0..252 step 4

  ushort4 o = make_ushort4(0, 0, 0, 0);
  if (w < W_DIM) {
    const size_t soff = (((size_t)(b * 4 + h) * W_DIM + w) * 256 + c4);
    float4 v = *reinterpret_cast<const float4*>(src + soff);
    o.x = f2bf(v.x); o.y = f2bf(v.y); o.z = f2bf(v.z); o.w = f2bf(v.w);
  }
  const size_t doff = ((size_t)b * PADW + w) * DDIM + h * 256 + c4;
  *reinterpret_cast<ushort4*>(dst + doff) = o;
}

// ---------------------------------------------------------------------------
// Batched gram GEMM (NT, both operands [row][K] bf16, K=1024) with fused
// circular-diagonal-band reduction epilogue.
// grid (64, 16): x = it*8 + jt (128-tiles of padded 1024), y = batch.
// block 256 = 4 waves, each wave computes a 64x64 quadrant via 4x4 frags of
// v_mfma_f32_16x16x32_bf16.
// ---------------------------------------------------------------------------
__global__ void gemm_band_kernel(const unsigned short* __restrict__ A,
                                 const unsigned short* __restrict__ B,
                                 float* __restrict__ out) {
  const int b  = blockIdx.y;
  const int it = blockIdx.x >> 3;
  const int jt = blockIdx.x & 7;

  // LDS: staging As[128][32] + Bs[128][32] bf16 (16 KB), aliased by the
  // epilogue buffer Ep[64][132] fp32 (33792 B) after the K-loop.
  __shared__ __align__(16) unsigned char smem[64 * 132 * 4];
  unsigned short* As = (unsigned short*)smem;            // 8192 B
  unsigned short* Bs = (unsigned short*)(smem + 8192);   // 8192 B

  const int tid  = threadIdx.x;
  const int lane = tid & 63;
  const int warp = tid >> 6;
  const int wm   = warp >> 1;
  const int wn   = warp & 1;

  const unsigned short* Ab = A + ((size_t)(b * PADW + it * 128)) * DDIM;
  const unsigned short* Bb = B + ((size_t)(b * PADW + jt * 128)) * DDIM;

  // Staging map: wave `warp` owns tile rows [warp*32, warp*32+32).
  // One global_load_lds(16B) covers 16 rows: lane -> row base+lane/4, kchunk (lane&3)*8.
  // LDS layout [row][32] bf16 => byte offset = warp*2048 + lane*16 (wave-uniform + lane*16). 
  const int srow = warp * 32 + (lane >> 2);
  const int scol = (lane & 3) * 8;
  const unsigned short* gA0 = Ab + (size_t)srow * DDIM + scol;
  const unsigned short* gA1 = gA0 + (size_t)16 * DDIM;
  const unsigned short* gB0 = Bb + (size_t)srow * DDIM + scol;
  const unsigned short* gB1 = gB0 + (size_t)16 * DDIM;
  unsigned short* lA0 = &As[srow * 32 + scol];
  unsigned short* lA1 = &As[(srow + 16) * 32 + scol];
  unsigned short* lB0 = &Bs[srow * 32 + scol];
  unsigned short* lB1 = &Bs[(srow + 16) * 32 + scol];

  floatx4 acc[4][4];
#pragma unroll
  for (int i = 0; i < 4; ++i)
#pragma unroll
    for (int j = 0; j < 4; ++j) acc[i][j] = (floatx4)0.0f;

  const int quad = lane >> 4;
  const int r16  = lane & 15;
  // A frag: A[m=lane&15][k=quad*8+j]; B frag: B[n=lane&15][k=quad*8+j] (NT).
  const unsigned short* ArowBase = &As[(wm * 64 + r16) * 32 + quad * 8];
  const unsigned short* BrowBase = &Bs[(wn * 64 + r16) * 32 + quad * 8];

  for (int kt = 0; kt < DDIM / 32; ++kt) {
    __syncthreads();                       // prev ds_reads done before overwrite
    const int ko = kt * 32;
    async16(gA0 + ko, lA0);
    async16(gA1 + ko, lA1);
    async16(gB0 + ko, lB0);
    async16(gB1 + ko, lB1);
    __syncthreads();                       // drains vmcnt before barrier

    short8 af[4], bf[4];
#pragma unroll
    for (int mi = 0; mi < 4; ++mi)
      af[mi] = *(const short8*)(ArowBase + mi * 16 * 32);
#pragma unroll
    for (int ni = 0; ni < 4; ++ni)
      bf[ni] = *(const short8*)(BrowBase + ni * 16 * 32);
#pragma unroll
    for (int mi = 0; mi < 4; ++mi)
#pragma unroll
      for (int ni = 0; ni < 4; ++ni)
        acc[mi][ni] = __builtin_amdgcn_mfma_f32_16x16x32_bf16(
            af[mi], bf[ni], acc[mi][ni], 0, 0, 0);
  }

  // ---- Epilogue: reduce diagonals d = i - j; gram[i,j] -> out[b, (i-j-450) mod 900].
  // Two half-passes (64 rows each) so the Ep buffer fits in 33792 B of LDS.
  __syncthreads();                         // staging LDS dead; safe to alias
  float* Ep = (float*)smem;                // [64][132]
  const int di_base = it * 128 - jt * 128 - NPAD;

  for (int half = 0; half < 2; ++half) {
    if (wm == half) {
      // C/D layout: row = quad*4 + reg, col = lane&15 (m89-verified).
#pragma unroll
      for (int mi = 0; mi < 4; ++mi)
#pragma unroll
        for (int ni = 0; ni < 4; ++ni)
#pragma unroll
          for (int r = 0; r < 4; ++r) {
            const int lr = mi * 16 + quad * 4 + r;        // 0..63
            const int c  = wn * 64 + ni * 16 + r16;       // 0..127
            Ep[lr * 132 + c] = acc[mi][ni][r];
          }
    }
    __syncthreads();
    if (tid < 191) {
      const int d = tid - 127;             // i_local - j_local, [-127, 63]
      float s = 0.0f;
      for (int k = 0; k < 64; ++k) {       // i_local = k, j_local = k - d
        const int j = k - d;
        if ((unsigned)j < 128u) s += Ep[k * 132 + j];
      }
      int dg = di_base + half * 64 + d;    // global i - j - 450
      int sidx = dg % W_DIM;
      if (sidx < 0) sidx += W_DIM;
      atomicAdd(&out[b * W_DIM + sidx], s);
    }
    __syncthreads();
  }
}

// ---------------------------------------------------------------------------
// Fallback (only if workspace is too small): direct fp32 computation.
// ---------------------------------------------------------------------------
__global__ void naive_kernel(const float* __restrict__ x1,
                             const float* __restrict__ x2,
                             float* __restrict__ out) {
  const int s = blockIdx.x;   // 0..899
  const int b = blockIdx.y;   // 0..15
  const int c = threadIdx.x;  // 0..255
  float acc = 0.0f;
  for (int h = 0; h < 4; ++h) {
    const float* p1 = x1 + (size_t)(b * 4 + h) * W_DIM * 256;
    const float* p2 = x2 + (size_t)(b * 4 + h) * W_DIM * 256;
    for (int w = 0; w < W_DIM; ++w) {
      int w1 = s + w + NPAD;
      if (w1 >= W_DIM) w1 -= W_DIM;
      if (w1 >= W_DIM) w1 -= W_DIM;
      acc += p1[(size_t)w1 * 256 + c] * p2[(size_t)w * 256 + c];
    }
  }
  // block reduce
  for (int off = 32; off > 0; off >>= 1) acc += __shfl_down(acc, off, 64);
  __shared__ float red[4];
  if ((threadIdx.x & 63) == 0) red[threadIdx.x >> 6] = acc;
  __syncthreads();
  if (threadIdx.x == 0)
    out[b * W_DIM + s] = red[0] + red[1] + red[2] + red[3];
}

extern "C" void kernel_launch(void* const* d_in, const int* in_sizes, int n_in,
                              void* d_out, int out_size, void* d_ws, size_t ws_size,
                              hipStream_t stream) {
  const float* x1 = (const float*)d_in[0];
  const float* x2 = (const float*)d_in[1];
  float* out = (float*)d_out;

  hipMemsetAsync(d_out, 0, (size_t)out_size * sizeof(float), stream);

  const size_t need = (size_t)2 * 16 * PADW * DDIM * sizeof(unsigned short); // 64 MB
  if (ws_size >= need) {
    unsigned short* dA = (unsigned short*)d_ws;
    unsigned short* dB = dA + (size_t)16 * PADW * DDIM;
    convert_kernel<<<dim3(PADW, 16, 2), 256, 0, stream>>>(x1, x2, dA, dB);
    gemm_band_kernel<<<dim3(64, 16), 256, 0, stream>>>(dA, dB, out);
  } else {
    naive_kernel<<<dim3(W_DIM, 16), 256, 0, stream>>>(x1, x2, out);
  }
}